// Round 7
// baseline (394.125 us; speedup 1.0000x reference)
//
#include <hip/hip_runtime.h>
#include <hip/hip_bf16.h>
#include <math.h>

// GateFusion via bf16 MFMA (16x16x32). One-shot block structure (proven exact
// HBM traffic; loop-carried register prefetch spills at VGPR=64 budget and
// triples traffic -- rounds 3/4/6). LDS holds ONLY the phase-2 output weights
// (40 KB -> 4 blocks/CU, 32 waves/CU); phase-1 gate weights (20 KB,
// L3-resident) are read from cache -- TLP hides their latency.
// out = g * (x_d@W_d) + (1-g) * (x_c@W_c),
// g = sigmoid( relu(LN(concat@Wg1)) @ Wg2 ),  per row.
//
// d_ws: fragment-linear bf16 weights (see convert_weights):
//   frags 0..19 : Wg1  (ks 0..4) x (nt 0..3)   [K=160, N=64]
//   frags 20..59: [Wd;Wc] (ks 0..4) x (nt 0..7) [K=160, N=128]
// frag = 512 bf16: lane l holds B[k0+j][n], k0=ks*32+(l>>4)*8, n=nt*16+(l&15).

namespace {

typedef __attribute__((ext_vector_type(8))) short short8;
typedef __attribute__((ext_vector_type(4))) float f32x4;

constexpr int CD = 64, CC = 96, CH = 64, CF = 128;
constexpr int NFG1 = 20;   // gate-weight frags (read from L2/L3)
constexpr int NFCB = 40;   // combined-output-weight frags (staged in LDS)
constexpr int NFRAG = NFG1 + NFCB;
constexpr int WCHUNKS = NFCB * 512 * 2 / 16;  // 2560 x 16B = 40960 B

__device__ inline short bf16_of(float f) {
  __hip_bfloat16 h = __float2bfloat16(f);
  return *reinterpret_cast<short*>(&h);
}

__global__ void convert_weights(const float* __restrict__ Wd,
                                const float* __restrict__ Wc,
                                const float* __restrict__ Wg1,
                                short* __restrict__ ws) {
  const int t = blockIdx.x * 256 + threadIdx.x;
  if (t >= 64 * NFRAG) return;
  const int frag = t >> 6, l = t & 63;
  const int cidx = l & 15, kb = l >> 4;
  float v[8];
  if (frag < NFG1) {
    const int ks = frag >> 2, nt = frag & 3;
    const int n = nt * 16 + cidx, k0 = ks * 32 + kb * 8;
    #pragma unroll
    for (int j = 0; j < 8; ++j) v[j] = Wg1[(k0 + j) * CH + n];
  } else {
    const int f2 = frag - NFG1;
    const int ks = f2 >> 3, nt = f2 & 7;
    const int n = nt * 16 + cidx, k0 = ks * 32 + kb * 8;
    #pragma unroll
    for (int j = 0; j < 8; ++j) {
      const int k = k0 + j;
      v[j] = (k < CD) ? Wd[k * CF + n] : Wc[(k - CD) * CF + n];
    }
  }
  short8 o;
  #pragma unroll
  for (int j = 0; j < 8; ++j) o[j] = bf16_of(v[j]);
  *reinterpret_cast<short8*>(ws + frag * 512 + l * 8) = o;
}

__global__ __launch_bounds__(512, 8)
void gate_fusion_mfma(const float* __restrict__ xd,
                      const float* __restrict__ xc,
                      const float* __restrict__ gma,
                      const float* __restrict__ bta,
                      const float* __restrict__ Wg2,
                      const short* __restrict__ wf,
                      float* __restrict__ out, int N) {
  __shared__ short wlds[NFCB * 512];

  const int tid  = threadIdx.x;
  const int lane = tid & 63;
  const int wv   = tid >> 6;                 // 0..7
  const int r0   = blockIdx.x * 256 + wv * 32;
  const int cidx = lane & 15;
  const int kb   = lane >> 4;
  const bool active = (r0 < N);              // N % 32 == 0: whole-wave granularity

  // ---- issue this wave's x loads first (in flight under staging+barrier)
  f32x4 buf[2][5][2];
  if (active) {
    #pragma unroll
    for (int mt = 0; mt < 2; ++mt) {
      const size_t row = (size_t)(r0 + mt * 16 + cidx);
      const float* rd = xd + row * CD + kb * 8;
      const float* rc = xc + row * CC + kb * 8;
      #pragma unroll
      for (int ks = 0; ks < 5; ++ks) {
        const float* p = (ks < 2) ? (rd + ks * 32) : (rc + (ks - 2) * 32);
        buf[mt][ks][0] = *reinterpret_cast<const f32x4*>(p);
        buf[mt][ks][1] = *reinterpret_cast<const f32x4*>(p + 4);
      }
    }
  }

  // ---- stage the 40 output-weight frags (40960 B) into LDS
  {
    const short* wsrc = wf + NFG1 * 512;
    #pragma unroll
    for (int it = 0; it < WCHUNKS / 512; ++it) {
      const int c = tid + it * 512;
      short8 v = *reinterpret_cast<const short8*>(wsrc + (size_t)c * 8);
      *reinterpret_cast<short8*>(&wlds[c * 8]) = v;
    }
  }
  __syncthreads();
  if (!active) return;   // after the only barrier

  // per-wave constants (cache-hit loads)
  float gmv[4], btv[4], w2v[4];
  #pragma unroll
  for (int nt = 0; nt < 4; ++nt) {
    const int c = nt * 16 + cidx;
    gmv[nt] = gma[c]; btv[nt] = bta[c]; w2v[nt] = Wg2[c];
  }

  // ---- convert x to bf16 A-fragments
  short8 xf[2][5];
  #pragma unroll
  for (int mt = 0; mt < 2; ++mt)
    #pragma unroll
    for (int ks = 0; ks < 5; ++ks) {
      short8 f;
      #pragma unroll
      for (int j = 0; j < 4; ++j) {
        f[j]     = bf16_of(buf[mt][ks][0][j]);
        f[4 + j] = bf16_of(buf[mt][ks][1][j]);
      }
      xf[mt][ks] = f;
    }

  // ---- phase 1: h = concat @ Wg1  [32 x 64]  (B-frags from L2/L3)
  const f32x4 vzero = {0.f, 0.f, 0.f, 0.f};
  f32x4 acc1[2][4];
  #pragma unroll
  for (int mt = 0; mt < 2; ++mt)
    #pragma unroll
    for (int nt = 0; nt < 4; ++nt) acc1[mt][nt] = vzero;

  #pragma unroll
  for (int ks = 0; ks < 5; ++ks) {
    short8 bg[4];
    #pragma unroll
    for (int nt = 0; nt < 4; ++nt)
      bg[nt] = *reinterpret_cast<const short8*>(wf + (ks * 4 + nt) * 512 + lane * 8);
    #pragma unroll
    for (int mt = 0; mt < 2; ++mt)
      #pragma unroll
      for (int nt = 0; nt < 4; ++nt)
        acc1[mt][nt] = __builtin_amdgcn_mfma_f32_16x16x32_bf16(
            xf[mt][ks], bg[nt], acc1[mt][nt], 0, 0, 0);
  }

  // ---- LayerNorm + relu + dot(Wg2) + sigmoid (C-fragment layout)
  float gate[2][4];
  #pragma unroll
  for (int mt = 0; mt < 2; ++mt) {
    float s[4], q[4];
    #pragma unroll
    for (int r = 0; r < 4; ++r) {
      s[r] = 0.f; q[r] = 0.f;
      #pragma unroll
      for (int nt = 0; nt < 4; ++nt) {
        const float c = acc1[mt][nt][r];
        s[r] += c; q[r] += c * c;
      }
    }
    #pragma unroll
    for (int m = 1; m < 16; m <<= 1)
      #pragma unroll
      for (int r = 0; r < 4; ++r) {
        s[r] += __shfl_xor(s[r], m, 64);
        q[r] += __shfl_xor(q[r], m, 64);
      }
    float p[4];
    #pragma unroll
    for (int r = 0; r < 4; ++r) {
      const float mu  = s[r] * (1.f / CH);
      const float var = q[r] * (1.f / CH) - mu * mu;
      const float rsd = rsqrtf(var + 1e-5f);
      float pp = 0.f;
      #pragma unroll
      for (int nt = 0; nt < 4; ++nt) {
        const float h = fmaxf((acc1[mt][nt][r] - mu) * rsd * gmv[nt] + btv[nt], 0.f);
        pp += h * w2v[nt];
      }
      p[r] = pp;
    }
    #pragma unroll
    for (int m = 1; m < 16; m <<= 1)
      #pragma unroll
      for (int r = 0; r < 4; ++r) p[r] += __shfl_xor(p[r], m, 64);
    #pragma unroll
    for (int r = 0; r < 4; ++r) gate[mt][r] = 1.f / (1.f + expf(-p[r]));
  }

  // ---- phase 2 in 4 nt-quarter slices: dual D/C accumulate, blend, store
  #pragma unroll
  for (int q = 0; q < 4; ++q) {
    f32x4 aD[2][2], aC[2][2];
    #pragma unroll
    for (int mt = 0; mt < 2; ++mt)
      #pragma unroll
      for (int nt = 0; nt < 2; ++nt) { aD[mt][nt] = vzero; aC[mt][nt] = vzero; }

    #pragma unroll
    for (int ks = 0; ks < 5; ++ks) {
      short8 bg[2];
      #pragma unroll
      for (int nt = 0; nt < 2; ++nt)
        bg[nt] = *reinterpret_cast<const short8*>(
            &wlds[(ks * 8 + q * 2 + nt) * 512 + lane * 8]);
      if (ks < 2) {
        #pragma unroll
        for (int mt = 0; mt < 2; ++mt)
          #pragma unroll
          for (int nt = 0; nt < 2; ++nt)
            aD[mt][nt] = __builtin_amdgcn_mfma_f32_16x16x32_bf16(
                xf[mt][ks], bg[nt], aD[mt][nt], 0, 0, 0);
      } else {
        #pragma unroll
        for (int mt = 0; mt < 2; ++mt)
          #pragma unroll
          for (int nt = 0; nt < 2; ++nt)
            aC[mt][nt] = __builtin_amdgcn_mfma_f32_16x16x32_bf16(
                xf[mt][ks], bg[nt], aC[mt][nt], 0, 0, 0);
      }
    }

    #pragma unroll
    for (int mt = 0; mt < 2; ++mt) {
      const size_t rowb = (size_t)r0 + mt * 16 + kb * 4;
      #pragma unroll
      for (int nt = 0; nt < 2; ++nt) {
        #pragma unroll
        for (int r = 0; r < 4; ++r) {
          const float g = gate[mt][r];
          const float o = fmaf(g, aD[mt][nt][r] - aC[mt][nt][r], aC[mt][nt][r]);
          out[(rowb + r) * CF + (q * 2 + nt) * 16 + cidx] = o;
        }
      }
    }
  }
}

}  // namespace

extern "C" void kernel_launch(void* const* d_in, const int* in_sizes, int n_in,
                              void* d_out, int out_size, void* d_ws, size_t ws_size,
                              hipStream_t stream) {
  const float* xd  = (const float*)d_in[0];
  const float* xc  = (const float*)d_in[1];
  const float* Wd  = (const float*)d_in[2];
  const float* Wc  = (const float*)d_in[3];
  const float* Wg1 = (const float*)d_in[4];
  const float* gma = (const float*)d_in[5];
  const float* bta = (const float*)d_in[6];
  const float* Wg2 = (const float*)d_in[7];
  float* out = (float*)d_out;
  short* ws  = (short*)d_ws;   // needs 60 KB

  const int N = in_sizes[0] / CD;

  convert_weights<<<dim3(15), dim3(256), 0, stream>>>(Wd, Wc, Wg1, ws);

  const int nblk = (N + 255) / 256;   // 256 rows per 8-wave block
  gate_fusion_mfma<<<dim3(nblk), dim3(512), 0, stream>>>(
      xd, xc, gma, bta, Wg2, ws, out, N);
}

// Round 8
// 143.004 us; speedup vs baseline: 2.7560x; 2.7560x over previous
//
#include <hip/hip_runtime.h>
#include <hip/hip_bf16.h>
#include <math.h>

// GateFusion via bf16 MFMA (16x16x32). One-shot block structure (proven exact
// HBM traffic). LDS holds ONLY the phase-2 output weights (40 KB -> 4
// blocks/CU); phase-1 gate weights (20 KB, L2/L3-resident) read from cache.
// launch_bounds(512,4): VGPR cap 128 -- (512,8) forced VGPR=32 and spilled
// everything to scratch (round 7: WRITE 847MB, 394us).
// out = g * (x_d@W_d) + (1-g) * (x_c@W_c),
// g = sigmoid( relu(LN(concat@Wg1)) @ Wg2 ),  per row.
//
// d_ws: fragment-linear bf16 weights (see convert_weights):
//   frags 0..19 : Wg1  (ks 0..4) x (nt 0..3)   [K=160, N=64]
//   frags 20..59: [Wd;Wc] (ks 0..4) x (nt 0..7) [K=160, N=128]
// frag = 512 bf16: lane l holds B[k0+j][n], k0=ks*32+(l>>4)*8, n=nt*16+(l&15).

namespace {

typedef __attribute__((ext_vector_type(8))) short short8;
typedef __attribute__((ext_vector_type(4))) float f32x4;

constexpr int CD = 64, CC = 96, CH = 64, CF = 128;
constexpr int NFG1 = 20;   // gate-weight frags (read from L2/L3)
constexpr int NFCB = 40;   // combined-output-weight frags (staged in LDS)
constexpr int NFRAG = NFG1 + NFCB;
constexpr int WCHUNKS = NFCB * 512 * 2 / 16;  // 2560 x 16B = 40960 B

__device__ inline short bf16_of(float f) {
  __hip_bfloat16 h = __float2bfloat16(f);
  return *reinterpret_cast<short*>(&h);
}

__global__ void convert_weights(const float* __restrict__ Wd,
                                const float* __restrict__ Wc,
                                const float* __restrict__ Wg1,
                                short* __restrict__ ws) {
  const int t = blockIdx.x * 256 + threadIdx.x;
  if (t >= 64 * NFRAG) return;
  const int frag = t >> 6, l = t & 63;
  const int cidx = l & 15, kb = l >> 4;
  float v[8];
  if (frag < NFG1) {
    const int ks = frag >> 2, nt = frag & 3;
    const int n = nt * 16 + cidx, k0 = ks * 32 + kb * 8;
    #pragma unroll
    for (int j = 0; j < 8; ++j) v[j] = Wg1[(k0 + j) * CH + n];
  } else {
    const int f2 = frag - NFG1;
    const int ks = f2 >> 3, nt = f2 & 7;
    const int n = nt * 16 + cidx, k0 = ks * 32 + kb * 8;
    #pragma unroll
    for (int j = 0; j < 8; ++j) {
      const int k = k0 + j;
      v[j] = (k < CD) ? Wd[k * CF + n] : Wc[(k - CD) * CF + n];
    }
  }
  short8 o;
  #pragma unroll
  for (int j = 0; j < 8; ++j) o[j] = bf16_of(v[j]);
  *reinterpret_cast<short8*>(ws + frag * 512 + l * 8) = o;
}

__global__ __launch_bounds__(512, 4)
void gate_fusion_mfma(const float* __restrict__ xd,
                      const float* __restrict__ xc,
                      const float* __restrict__ gma,
                      const float* __restrict__ bta,
                      const float* __restrict__ Wg2,
                      const short* __restrict__ wf,
                      float* __restrict__ out, int N) {
  __shared__ short wlds[NFCB * 512];

  const int tid  = threadIdx.x;
  const int lane = tid & 63;
  const int wv   = tid >> 6;                 // 0..7
  const int r0   = blockIdx.x * 256 + wv * 32;
  const int cidx = lane & 15;
  const int kb   = lane >> 4;
  const bool active = (r0 < N);              // N % 32 == 0: whole-wave granularity

  // ---- issue this wave's x loads first (in flight under staging+barrier)
  f32x4 buf[2][5][2];
  if (active) {
    #pragma unroll
    for (int mt = 0; mt < 2; ++mt) {
      const size_t row = (size_t)(r0 + mt * 16 + cidx);
      const float* rd = xd + row * CD + kb * 8;
      const float* rc = xc + row * CC + kb * 8;
      #pragma unroll
      for (int ks = 0; ks < 5; ++ks) {
        const float* p = (ks < 2) ? (rd + ks * 32) : (rc + (ks - 2) * 32);
        buf[mt][ks][0] = *reinterpret_cast<const f32x4*>(p);
        buf[mt][ks][1] = *reinterpret_cast<const f32x4*>(p + 4);
      }
    }
  }

  // ---- stage the 40 output-weight frags (40960 B) into LDS
  {
    const short* wsrc = wf + NFG1 * 512;
    #pragma unroll
    for (int it = 0; it < WCHUNKS / 512; ++it) {
      const int c = tid + it * 512;
      short8 v = *reinterpret_cast<const short8*>(wsrc + (size_t)c * 8);
      *reinterpret_cast<short8*>(&wlds[c * 8]) = v;
    }
  }
  __syncthreads();
  if (!active) return;   // after the only barrier

  // per-wave constants (cache-hit loads)
  float gmv[4], btv[4], w2v[4];
  #pragma unroll
  for (int nt = 0; nt < 4; ++nt) {
    const int c = nt * 16 + cidx;
    gmv[nt] = gma[c]; btv[nt] = bta[c]; w2v[nt] = Wg2[c];
  }

  // ---- convert x to bf16 A-fragments
  short8 xf[2][5];
  #pragma unroll
  for (int mt = 0; mt < 2; ++mt)
    #pragma unroll
    for (int ks = 0; ks < 5; ++ks) {
      short8 f;
      #pragma unroll
      for (int j = 0; j < 4; ++j) {
        f[j]     = bf16_of(buf[mt][ks][0][j]);
        f[4 + j] = bf16_of(buf[mt][ks][1][j]);
      }
      xf[mt][ks] = f;
    }

  // ---- phase 1: h = concat @ Wg1  [32 x 64]  (B-frags from L2/L3)
  const f32x4 vzero = {0.f, 0.f, 0.f, 0.f};
  f32x4 acc1[2][4];
  #pragma unroll
  for (int mt = 0; mt < 2; ++mt)
    #pragma unroll
    for (int nt = 0; nt < 4; ++nt) acc1[mt][nt] = vzero;

  #pragma unroll
  for (int ks = 0; ks < 5; ++ks) {
    short8 bg[4];
    #pragma unroll
    for (int nt = 0; nt < 4; ++nt)
      bg[nt] = *reinterpret_cast<const short8*>(wf + (ks * 4 + nt) * 512 + lane * 8);
    #pragma unroll
    for (int mt = 0; mt < 2; ++mt)
      #pragma unroll
      for (int nt = 0; nt < 4; ++nt)
        acc1[mt][nt] = __builtin_amdgcn_mfma_f32_16x16x32_bf16(
            xf[mt][ks], bg[nt], acc1[mt][nt], 0, 0, 0);
  }

  // ---- LayerNorm + relu + dot(Wg2) + sigmoid (C-fragment layout)
  float gate[2][4];
  #pragma unroll
  for (int mt = 0; mt < 2; ++mt) {
    float s[4], q[4];
    #pragma unroll
    for (int r = 0; r < 4; ++r) {
      s[r] = 0.f; q[r] = 0.f;
      #pragma unroll
      for (int nt = 0; nt < 4; ++nt) {
        const float c = acc1[mt][nt][r];
        s[r] += c; q[r] += c * c;
      }
    }
    #pragma unroll
    for (int m = 1; m < 16; m <<= 1)
      #pragma unroll
      for (int r = 0; r < 4; ++r) {
        s[r] += __shfl_xor(s[r], m, 64);
        q[r] += __shfl_xor(q[r], m, 64);
      }
    float p[4];
    #pragma unroll
    for (int r = 0; r < 4; ++r) {
      const float mu  = s[r] * (1.f / CH);
      const float var = q[r] * (1.f / CH) - mu * mu;
      const float rsd = rsqrtf(var + 1e-5f);
      float pp = 0.f;
      #pragma unroll
      for (int nt = 0; nt < 4; ++nt) {
        const float h = fmaxf((acc1[mt][nt][r] - mu) * rsd * gmv[nt] + btv[nt], 0.f);
        pp += h * w2v[nt];
      }
      p[r] = pp;
    }
    #pragma unroll
    for (int m = 1; m < 16; m <<= 1)
      #pragma unroll
      for (int r = 0; r < 4; ++r) p[r] += __shfl_xor(p[r], m, 64);
    #pragma unroll
    for (int r = 0; r < 4; ++r) gate[mt][r] = 1.f / (1.f + expf(-p[r]));
  }

  // ---- phase 2 in 4 nt-quarter slices: dual D/C accumulate, blend, store
  #pragma unroll
  for (int q = 0; q < 4; ++q) {
    f32x4 aD[2][2], aC[2][2];
    #pragma unroll
    for (int mt = 0; mt < 2; ++mt)
      #pragma unroll
      for (int nt = 0; nt < 2; ++nt) { aD[mt][nt] = vzero; aC[mt][nt] = vzero; }

    #pragma unroll
    for (int ks = 0; ks < 5; ++ks) {
      short8 bg[2];
      #pragma unroll
      for (int nt = 0; nt < 2; ++nt)
        bg[nt] = *reinterpret_cast<const short8*>(
            &wlds[(ks * 8 + q * 2 + nt) * 512 + lane * 8]);
      if (ks < 2) {
        #pragma unroll
        for (int mt = 0; mt < 2; ++mt)
          #pragma unroll
          for (int nt = 0; nt < 2; ++nt)
            aD[mt][nt] = __builtin_amdgcn_mfma_f32_16x16x32_bf16(
                xf[mt][ks], bg[nt], aD[mt][nt], 0, 0, 0);
      } else {
        #pragma unroll
        for (int mt = 0; mt < 2; ++mt)
          #pragma unroll
          for (int nt = 0; nt < 2; ++nt)
            aC[mt][nt] = __builtin_amdgcn_mfma_f32_16x16x32_bf16(
                xf[mt][ks], bg[nt], aC[mt][nt], 0, 0, 0);
      }
    }

    #pragma unroll
    for (int mt = 0; mt < 2; ++mt) {
      const size_t rowb = (size_t)r0 + mt * 16 + kb * 4;
      #pragma unroll
      for (int nt = 0; nt < 2; ++nt) {
        #pragma unroll
        for (int r = 0; r < 4; ++r) {
          const float g = gate[mt][r];
          const float o = fmaf(g, aD[mt][nt][r] - aC[mt][nt][r], aC[mt][nt][r]);
          out[(rowb + r) * CF + (q * 2 + nt) * 16 + cidx] = o;
        }
      }
    }
  }
}

}  // namespace

extern "C" void kernel_launch(void* const* d_in, const int* in_sizes, int n_in,
                              void* d_out, int out_size, void* d_ws, size_t ws_size,
                              hipStream_t stream) {
  const float* xd  = (const float*)d_in[0];
  const float* xc  = (const float*)d_in[1];
  const float* Wd  = (const float*)d_in[2];
  const float* Wc  = (const float*)d_in[3];
  const float* Wg1 = (const float*)d_in[4];
  const float* gma = (const float*)d_in[5];
  const float* bta = (const float*)d_in[6];
  const float* Wg2 = (const float*)d_in[7];
  float* out = (float*)d_out;
  short* ws  = (short*)d_ws;   // needs 60 KB

  const int N = in_sizes[0] / CD;

  convert_weights<<<dim3(15), dim3(256), 0, stream>>>(Wd, Wc, Wg1, ws);

  const int nblk = (N + 255) / 256;   // 256 rows per 8-wave block
  gate_fusion_mfma<<<dim3(nblk), dim3(512), 0, stream>>>(
      xd, xc, gma, bta, Wg2, ws, out, N);
}

// Round 9
// 134.723 us; speedup vs baseline: 2.9255x; 1.0615x over previous
//
#include <hip/hip_runtime.h>
#include <hip/hip_bf16.h>
#include <math.h>

// GateFusion via bf16 MFMA (16x16x32). One-shot block structure (proven exact
// HBM traffic). 16 rows per wave (was 32): halves per-wave register footprint
// (buf 80->40 VGPR) so (a) more waves/SIMD fit -- occupancy was capped ~16
// waves/CU by VGPR+AGPR ~128/wave -- and (b) the whole x-load burst stays in
// flight instead of being serialized by regalloc.
// LDS holds the phase-2 output weights (40 KB); phase-1 gate weights read
// from L2/L3. launch_bounds(512,4) -- (512,8) forced VGPR=32 + spill (r7).
// out = g * (x_d@W_d) + (1-g) * (x_c@W_c),
// g = sigmoid( relu(LN(concat@Wg1)) @ Wg2 ),  per row.
//
// d_ws: fragment-linear bf16 weights (see convert_weights):
//   frags 0..19 : Wg1  (ks 0..4) x (nt 0..3)   [K=160, N=64]
//   frags 20..59: [Wd;Wc] (ks 0..4) x (nt 0..7) [K=160, N=128]
// frag = 512 bf16: lane l holds B[k0+j][n], k0=ks*32+(l>>4)*8, n=nt*16+(l&15).

namespace {

typedef __attribute__((ext_vector_type(8))) short short8;
typedef __attribute__((ext_vector_type(4))) float f32x4;

constexpr int CD = 64, CC = 96, CH = 64, CF = 128;
constexpr int NFG1 = 20;   // gate-weight frags (read from L2/L3)
constexpr int NFCB = 40;   // combined-output-weight frags (staged in LDS)
constexpr int NFRAG = NFG1 + NFCB;
constexpr int WCHUNKS = NFCB * 512 * 2 / 16;  // 2560 x 16B = 40960 B

__device__ inline short bf16_of(float f) {
  __hip_bfloat16 h = __float2bfloat16(f);
  return *reinterpret_cast<short*>(&h);
}

__global__ void convert_weights(const float* __restrict__ Wd,
                                const float* __restrict__ Wc,
                                const float* __restrict__ Wg1,
                                short* __restrict__ ws) {
  const int t = blockIdx.x * 256 + threadIdx.x;
  if (t >= 64 * NFRAG) return;
  const int frag = t >> 6, l = t & 63;
  const int cidx = l & 15, kb = l >> 4;
  float v[8];
  if (frag < NFG1) {
    const int ks = frag >> 2, nt = frag & 3;
    const int n = nt * 16 + cidx, k0 = ks * 32 + kb * 8;
    #pragma unroll
    for (int j = 0; j < 8; ++j) v[j] = Wg1[(k0 + j) * CH + n];
  } else {
    const int f2 = frag - NFG1;
    const int ks = f2 >> 3, nt = f2 & 7;
    const int n = nt * 16 + cidx, k0 = ks * 32 + kb * 8;
    #pragma unroll
    for (int j = 0; j < 8; ++j) {
      const int k = k0 + j;
      v[j] = (k < CD) ? Wd[k * CF + n] : Wc[(k - CD) * CF + n];
    }
  }
  short8 o;
  #pragma unroll
  for (int j = 0; j < 8; ++j) o[j] = bf16_of(v[j]);
  *reinterpret_cast<short8*>(ws + frag * 512 + l * 8) = o;
}

__global__ __launch_bounds__(512, 4)
void gate_fusion_mfma(const float* __restrict__ xd,
                      const float* __restrict__ xc,
                      const float* __restrict__ gma,
                      const float* __restrict__ bta,
                      const float* __restrict__ Wg2,
                      const short* __restrict__ wf,
                      float* __restrict__ out, int N) {
  __shared__ short wlds[NFCB * 512];

  const int tid  = threadIdx.x;
  const int lane = tid & 63;
  const int wv   = tid >> 6;                 // 0..7
  const int r0   = blockIdx.x * 128 + wv * 16;   // 16 rows per wave
  const int cidx = lane & 15;
  const int kb   = lane >> 4;
  const bool active = (r0 < N);              // N % 16 == 0: whole-wave granularity

  // ---- issue this wave's x loads first (in flight under staging+barrier)
  f32x4 buf[5][2];
  if (active) {
    const size_t row = (size_t)(r0 + cidx);
    const float* rd = xd + row * CD + kb * 8;
    const float* rc = xc + row * CC + kb * 8;
    #pragma unroll
    for (int ks = 0; ks < 5; ++ks) {
      const float* p = (ks < 2) ? (rd + ks * 32) : (rc + (ks - 2) * 32);
      buf[ks][0] = *reinterpret_cast<const f32x4*>(p);
      buf[ks][1] = *reinterpret_cast<const f32x4*>(p + 4);
    }
  }

  // ---- stage the 40 output-weight frags (40960 B) into LDS
  {
    const short* wsrc = wf + NFG1 * 512;
    #pragma unroll
    for (int it = 0; it < WCHUNKS / 512; ++it) {
      const int c = tid + it * 512;
      short8 v = *reinterpret_cast<const short8*>(wsrc + (size_t)c * 8);
      *reinterpret_cast<short8*>(&wlds[c * 8]) = v;
    }
  }
  __syncthreads();
  if (!active) return;   // after the only barrier

  // per-wave constants (cache-hit loads)
  float gmv[4], btv[4], w2v[4];
  #pragma unroll
  for (int nt = 0; nt < 4; ++nt) {
    const int c = nt * 16 + cidx;
    gmv[nt] = gma[c]; btv[nt] = bta[c]; w2v[nt] = Wg2[c];
  }

  // ---- convert x to bf16 A-fragments
  short8 xf[5];
  #pragma unroll
  for (int ks = 0; ks < 5; ++ks) {
    short8 f;
    #pragma unroll
    for (int j = 0; j < 4; ++j) {
      f[j]     = bf16_of(buf[ks][0][j]);
      f[4 + j] = bf16_of(buf[ks][1][j]);
    }
    xf[ks] = f;
  }

  // ---- phase 1: h = x @ Wg1  [16 x 64]  (B-frags from L2/L3)
  const f32x4 vzero = {0.f, 0.f, 0.f, 0.f};
  f32x4 acc1[4];
  #pragma unroll
  for (int nt = 0; nt < 4; ++nt) acc1[nt] = vzero;

  #pragma unroll
  for (int ks = 0; ks < 5; ++ks) {
    short8 bg[4];
    #pragma unroll
    for (int nt = 0; nt < 4; ++nt)
      bg[nt] = *reinterpret_cast<const short8*>(wf + (ks * 4 + nt) * 512 + lane * 8);
    #pragma unroll
    for (int nt = 0; nt < 4; ++nt)
      acc1[nt] = __builtin_amdgcn_mfma_f32_16x16x32_bf16(
          xf[ks], bg[nt], acc1[nt], 0, 0, 0);
  }

  // ---- LayerNorm + relu + dot(Wg2) + sigmoid (C-fragment layout)
  float gate[4];
  {
    float s[4], q[4];
    #pragma unroll
    for (int r = 0; r < 4; ++r) {
      s[r] = 0.f; q[r] = 0.f;
      #pragma unroll
      for (int nt = 0; nt < 4; ++nt) {
        const float c = acc1[nt][r];
        s[r] += c; q[r] += c * c;
      }
    }
    #pragma unroll
    for (int m = 1; m < 16; m <<= 1)
      #pragma unroll
      for (int r = 0; r < 4; ++r) {
        s[r] += __shfl_xor(s[r], m, 64);
        q[r] += __shfl_xor(q[r], m, 64);
      }
    float p[4];
    #pragma unroll
    for (int r = 0; r < 4; ++r) {
      const float mu  = s[r] * (1.f / CH);
      const float var = q[r] * (1.f / CH) - mu * mu;
      const float rsd = rsqrtf(var + 1e-5f);
      float pp = 0.f;
      #pragma unroll
      for (int nt = 0; nt < 4; ++nt) {
        const float h = fmaxf((acc1[nt][r] - mu) * rsd * gmv[nt] + btv[nt], 0.f);
        pp += h * w2v[nt];
      }
      p[r] = pp;
    }
    #pragma unroll
    for (int m = 1; m < 16; m <<= 1)
      #pragma unroll
      for (int r = 0; r < 4; ++r) p[r] += __shfl_xor(p[r], m, 64);
    #pragma unroll
    for (int r = 0; r < 4; ++r) gate[r] = 1.f / (1.f + expf(-p[r]));
  }

  // ---- phase 2 in 4 nt-quarter slices: dual D/C accumulate, blend, store
  #pragma unroll
  for (int q = 0; q < 4; ++q) {
    f32x4 aD[2], aC[2];
    #pragma unroll
    for (int nt = 0; nt < 2; ++nt) { aD[nt] = vzero; aC[nt] = vzero; }

    #pragma unroll
    for (int ks = 0; ks < 5; ++ks) {
      short8 bg[2];
      #pragma unroll
      for (int nt = 0; nt < 2; ++nt)
        bg[nt] = *reinterpret_cast<const short8*>(
            &wlds[(ks * 8 + q * 2 + nt) * 512 + lane * 8]);
      if (ks < 2) {
        #pragma unroll
        for (int nt = 0; nt < 2; ++nt)
          aD[nt] = __builtin_amdgcn_mfma_f32_16x16x32_bf16(
              xf[ks], bg[nt], aD[nt], 0, 0, 0);
      } else {
        #pragma unroll
        for (int nt = 0; nt < 2; ++nt)
          aC[nt] = __builtin_amdgcn_mfma_f32_16x16x32_bf16(
              xf[ks], bg[nt], aC[nt], 0, 0, 0);
      }
    }

    {
      const size_t rowb = (size_t)r0 + kb * 4;
      #pragma unroll
      for (int nt = 0; nt < 2; ++nt) {
        #pragma unroll
        for (int r = 0; r < 4; ++r) {
          const float g = gate[r];
          const float o = fmaf(g, aD[nt][r] - aC[nt][r], aC[nt][r]);
          out[(rowb + r) * CF + (q * 2 + nt) * 16 + cidx] = o;
        }
      }
    }
  }
}

}  // namespace

extern "C" void kernel_launch(void* const* d_in, const int* in_sizes, int n_in,
                              void* d_out, int out_size, void* d_ws, size_t ws_size,
                              hipStream_t stream) {
  const float* xd  = (const float*)d_in[0];
  const float* xc  = (const float*)d_in[1];
  const float* Wd  = (const float*)d_in[2];
  const float* Wc  = (const float*)d_in[3];
  const float* Wg1 = (const float*)d_in[4];
  const float* gma = (const float*)d_in[5];
  const float* bta = (const float*)d_in[6];
  const float* Wg2 = (const float*)d_in[7];
  float* out = (float*)d_out;
  short* ws  = (short*)d_ws;   // needs 60 KB

  const int N = in_sizes[0] / CD;

  convert_weights<<<dim3(15), dim3(256), 0, stream>>>(Wd, Wc, Wg1, ws);

  const int nblk = (N + 127) / 128;   // 128 rows per 8-wave block
  gate_fusion_mfma<<<dim3(nblk), dim3(512), 0, stream>>>(
      xd, xc, gma, bta, Wg2, ws, out, N);
}